// Round 1
// baseline (391.471 us; speedup 1.0000x reference)
//
#include <hip/hip_runtime.h>

typedef __attribute__((ext_vector_type(8))) short short8;
typedef __attribute__((ext_vector_type(4))) float f32x4;

#define IN_CH   64
#define OUT_CH  128
#define PATCH   576          // 64 ch * 9 kernel positions, i = c*9 + (kh*3+kw)
#define KPAD    4608         // 576 * 8 features (silu, b0..b5, zero-pad)
#define XS_H    4
#define XS_W    66
#define XS_C    68           // pad 64 -> 68: read stride 68 words => 2-way max (free)
#define BS_STRIDE 40         // 32 + 8 pad: (5n+q) mod 8 uniform superbank spread

__device__ __forceinline__ unsigned short f2bf(float x) {
    union { float f; unsigned u; } v; v.f = x;
    unsigned r = v.u + 0x7FFFu + ((v.u >> 16) & 1u);   // RNE bf16
    return (unsigned short)(r >> 16);
}

// Build WbT[128][4608] bf16: k = i*8 + f; f=0 -> base_w, f=1..6 -> spline_w, f=7 -> 0
__global__ void prep_w_kernel(const float* __restrict__ base_w,
                              const float* __restrict__ spline_w,
                              unsigned short* __restrict__ wbt) {
    int idx = blockIdx.x * 256 + threadIdx.x;
    if (idx >= OUT_CH * PATCH) return;
    int o = idx / PATCH;
    int i = idx - o * PATCH;
    union { unsigned short u[8]; int4 v; } pk;
    pk.u[0] = f2bf(base_w[o * PATCH + i]);
    const float* s = spline_w + (size_t)(o * PATCH + i) * 6;
#pragma unroll
    for (int f = 0; f < 6; ++f) pk.u[1 + f] = f2bf(s[f]);
    pk.u[7] = 0;
    *(int4*)(wbt + ((size_t)o * KPAD + i * 8)) = pk.v;
}

// Fused ConvKAN: block = 128 rows (2 image lines) x 128 outputs.
// 4 waves, wave = 32m x 128n. A-frags built in-register from on-the-fly features.
__global__ __launch_bounds__(256, 1)
void convkan_main(const float* __restrict__ x,
                  const float* __restrict__ bias,
                  const unsigned short* __restrict__ wbt,
                  float* __restrict__ out) {
    extern __shared__ char smem[];
    float* Xs = (float*)smem;                                  // [4][66][68] fp32
    unsigned short* Bs = (unsigned short*)(smem + XS_H * XS_W * XS_C * 4); // [128][40] bf16

    const int tid  = threadIdx.x;
    const int blk  = blockIdx.x;
    const int lane = tid & 63;
    const int wave = tid >> 6;
    const int l16  = lane & 15;
    const int quad = lane >> 4;

    // ---- stage X: lines h0-1 .. h0+2 of image b, w padded +-1, c padded to 68 ----
    const int L  = blk * 2;              // line index 0..511
    const int b  = L >> 6;
    const int h0 = L & 63;
    const float* xb = x + ((size_t)b << 18);   // b * 64*64*64
    for (int idx = tid; idx < XS_H * XS_W * 16; idx += 256) {
        int hs  = idx / (XS_W * 16);
        int rem = idx - hs * (XS_W * 16);
        int wp  = rem >> 4;
        int c4  = rem & 15;
        int h = h0 - 1 + hs;
        int w = wp - 1;
        float4 v = make_float4(0.f, 0.f, 0.f, 0.f);
        if (h >= 0 && h < 64 && w >= 0 && w < 64)
            v = *(const float4*)(xb + (((h << 6) + w) << 6) + (c4 << 2));
        *(float4*)(Xs + (hs * XS_W + wp) * XS_C + (c4 << 2)) = v;
    }

    float bias_v[8];
#pragma unroll
    for (int ns = 0; ns < 8; ++ns) bias_v[ns] = bias[ns * 16 + l16];

    __syncthreads();

    f32x4 acc[2][8];
#pragma unroll
    for (int ms = 0; ms < 2; ++ms)
#pragma unroll
        for (int ns = 0; ns < 8; ++ns) acc[ms][ns] = (f32x4){0.f, 0.f, 0.f, 0.f};

    const int mrow0 = wave * 32 + l16;        // m-subtile 0 row (block-local)
    const int mrow1 = mrow0 + 16;             // m-subtile 1 row

    for (int it = 0; it < 144; ++it) {
        const int kb = it * 32;               // K base (4 patch elems per iter)

        // ---- stage B tile: Bs[n][0..31] = WbT[n][kb..kb+31], n-major for 16B frag reads
        {
            int n    = tid >> 1;
            int half = tid & 1;
            const int4* s4 = (const int4*)(wbt + (size_t)n * KPAD + kb + half * 16);
            int4* d4 = (int4*)(Bs + n * BS_STRIDE + half * 16);
            d4[0] = s4[0];
            d4[1] = s4[1];
        }
        __syncthreads();

        // ---- features -> A fragments (1 scalar per lane per m-subtile) ----
        const int i  = it * 4 + quad;         // patch element handled by this quad
        const int c  = i / 9;
        const int s9 = i - c * 9;
        const int kh = s9 / 3;
        const int kw = s9 - kh * 3;

        short8 afrag[2];
#pragma unroll
        for (int ms = 0; ms < 2; ++ms) {
            const int mloc = (ms == 0) ? mrow0 : mrow1;   // 0..127
            const int line = mloc >> 6;
            const int w    = mloc & 63;
            float p = Xs[((line + kh) * XS_W + (w + kw)) * XS_C + c];

            // silu
            float sig = 1.f / (1.f + __expf(-p));
            float f0  = p * sig;

            // cardinal cubic B-spline, uniform knots -3 + j*(2/3)
            float u  = (p + 3.0f) * 1.5f;
            float fj = floorf(u);
            int   j0 = (int)fj;
            float t  = u - fj;
            bool  inr = (u >= 0.f) & (u < 9.f);
            float t2 = t * t, t3 = t2 * t;
            const float c16 = 1.f / 6.f;
            float r0 = t3 * c16;
            float r1 = (-3.f * t3 + 3.f * t2 + 3.f * t + 1.f) * c16;
            float r2 = (3.f * t3 - 6.f * t2 + 4.f) * c16;
            float s1 = 1.f - t;
            float r3 = s1 * s1 * s1 * c16;

            unsigned short uf[8];
            uf[0] = f2bf(f0);
#pragma unroll
            for (int g = 0; g < 6; ++g) {
                int r = j0 - g;
                float v = (r == 0) ? r0 : ((r == 1) ? r1 : ((r == 2) ? r2 : ((r == 3) ? r3 : 0.f)));
                v = inr ? v : 0.f;
                uf[1 + g] = f2bf(v);
            }
            uf[7] = 0;
            short8 a;
#pragma unroll
            for (int e = 0; e < 8; ++e) a[e] = (short)uf[e];
            afrag[ms] = a;
        }

        // ---- MFMA ----
#pragma unroll
        for (int ns = 0; ns < 8; ++ns) {
            short8 bfrag = *(const short8*)(Bs + (ns * 16 + l16) * BS_STRIDE + quad * 8);
            acc[0][ns] = __builtin_amdgcn_mfma_f32_16x16x32_bf16(afrag[0], bfrag, acc[0][ns], 0, 0, 0);
            acc[1][ns] = __builtin_amdgcn_mfma_f32_16x16x32_bf16(afrag[1], bfrag, acc[1][ns], 0, 0, 0);
        }
        __syncthreads();
    }

    // ---- epilogue: C/D layout col=lane&15, row=quad*4+reg ----
    const size_t rowbase = (size_t)blk * 128 + wave * 32;
#pragma unroll
    for (int ms = 0; ms < 2; ++ms) {
#pragma unroll
        for (int r = 0; r < 4; ++r) {
            size_t row = rowbase + ms * 16 + quad * 4 + r;
            float* po = out + row * 128 + l16;
#pragma unroll
            for (int ns = 0; ns < 8; ++ns)
                po[ns * 16] = acc[ms][ns][r] + bias_v[ns];
        }
    }
}

extern "C" void kernel_launch(void* const* d_in, const int* in_sizes, int n_in,
                              void* d_out, int out_size, void* d_ws, size_t ws_size,
                              hipStream_t stream) {
    (void)in_sizes; (void)n_in; (void)out_size; (void)ws_size;
    const float* x        = (const float*)d_in[0];
    const float* base_w   = (const float*)d_in[1];
    const float* spline_w = (const float*)d_in[2];
    const float* bias     = (const float*)d_in[3];
    float* out = (float*)d_out;
    unsigned short* wbt = (unsigned short*)d_ws;   // 128*4608*2 = 1.13 MB

    hipLaunchKernelGGL(prep_w_kernel, dim3((OUT_CH * PATCH + 255) / 256), dim3(256), 0, stream,
                       base_w, spline_w, wbt);

    const int shmem = XS_H * XS_W * XS_C * 4 + 128 * BS_STRIDE * 2;  // 82048 B
    (void)hipFuncSetAttribute((const void*)convkan_main,
                              hipFuncAttributeMaxDynamicSharedMemorySize, shmem);
    hipLaunchKernelGGL(convkan_main, dim3(256), dim3(256), shmem, stream,
                       x, bias, wbt, out);
}

// Round 2
// 255.900 us; speedup vs baseline: 1.5298x; 1.5298x over previous
//
#include <hip/hip_runtime.h>

typedef __attribute__((ext_vector_type(8))) short short8;
typedef __attribute__((ext_vector_type(4))) float f32x4;

#define IN_CH   64
#define OUT_CH  128
#define PATCH   576          // i = c*9 + (kh*3+kw)
#define KPAD    4608         // 576 * 8 features (silu, b0..b5, zero-pad)
#define XS_W    66
#define XS_C    68           // stride 68 bf16 => lane stride 34 banks -> even banks, ~2-way (free)
#define BS_STRIDE 40         // 32 + 8 pad shorts
#define BS_SZ   (128 * BS_STRIDE)   // one B buffer, in shorts
#define NITER   144

__device__ __forceinline__ unsigned short f2bf(float x) {
    union { float f; unsigned u; } v; v.f = x;
    unsigned r = v.u + 0x7FFFu + ((v.u >> 16) & 1u);   // RNE bf16
    return (unsigned short)(r >> 16);
}
__device__ __forceinline__ float bf2f(unsigned short b) {
    union { unsigned u; float f; } v; v.u = ((unsigned)b) << 16;
    return v.f;
}

// Build WbT[128][4608] bf16: k = i*8 + f; f=0 -> base_w, f=1..6 -> spline_w, f=7 -> 0
__global__ void prep_w_kernel(const float* __restrict__ base_w,
                              const float* __restrict__ spline_w,
                              unsigned short* __restrict__ wbt) {
    int idx = blockIdx.x * 256 + threadIdx.x;
    if (idx >= OUT_CH * PATCH) return;
    int o = idx / PATCH;
    int i = idx - o * PATCH;
    union { unsigned short u[8]; int4 v; } pk;
    pk.u[0] = f2bf(base_w[o * PATCH + i]);
    const float* s = spline_w + (size_t)(o * PATCH + i) * 6;
#pragma unroll
    for (int f = 0; f < 6; ++f) pk.u[1 + f] = f2bf(s[f]);
    pk.u[7] = 0;
    *(int4*)(wbt + ((size_t)o * KPAD + i * 8)) = pk.v;
}

// Block = 64 rows (1 image line) x 128 outputs. 4 waves, wave = 16m x 128n.
// Xs bf16 (26.9 KB) + double-buffered Bs (20.5 KB) -> 47.4 KB LDS, 2 blocks/CU.
// One barrier per K-iter; B tile for it+1 prefetched into regs during compute of it.
__global__ __launch_bounds__(256, 2)
void convkan_main(const float* __restrict__ x,
                  const float* __restrict__ bias,
                  const unsigned short* __restrict__ wbt,
                  float* __restrict__ out) {
    extern __shared__ char smem[];
    unsigned short* Xs = (unsigned short*)smem;                 // [3][66][68] bf16
    unsigned short* Bs = Xs + 3 * XS_W * XS_C;                  // [2][128][40] bf16

    const int tid  = threadIdx.x;
    const int blk  = blockIdx.x;
    const int lane = tid & 63;
    const int wave = tid >> 6;
    const int l16  = lane & 15;
    const int quad = lane >> 4;

    // ---- stage X line h0-1..h0+1 of image b, w padded +-1, as bf16 ----
    const int L  = blk;                  // line index 0..511
    const int b  = L >> 6;
    const int h0 = L & 63;
    const float* xb = x + ((size_t)b << 18);   // b * 64*64*64
    for (int idx = tid; idx < 3 * XS_W * 16; idx += 256) {
        int hs  = idx / (XS_W * 16);
        int rem = idx - hs * (XS_W * 16);
        int wp  = rem >> 4;
        int c4  = rem & 15;
        int h = h0 - 1 + hs;
        int w = wp - 1;
        float4 v = make_float4(0.f, 0.f, 0.f, 0.f);
        if (h >= 0 && h < 64 && w >= 0 && w < 64)
            v = *(const float4*)(xb + (((h << 6) + w) << 6) + (c4 << 2));
        union { unsigned short us[4]; uint2 u2; } pk;
        pk.us[0] = f2bf(v.x); pk.us[1] = f2bf(v.y);
        pk.us[2] = f2bf(v.z); pk.us[3] = f2bf(v.w);
        *(uint2*)(Xs + (hs * XS_W + wp) * XS_C + (c4 << 2)) = pk.u2;
    }

    float bias_v[8];
#pragma unroll
    for (int ns = 0; ns < 8; ++ns) bias_v[ns] = bias[ns * 16 + l16];

    f32x4 acc[8];
#pragma unroll
    for (int ns = 0; ns < 8; ++ns) acc[ns] = (f32x4){0.f, 0.f, 0.f, 0.f};

    // B-prefetch addressing: thread covers 32 B of row n (n = tid>>1, half = tid&1)
    const int bn   = tid >> 1;
    const int half = tid & 1;
    const unsigned short* wsrc = wbt + (size_t)bn * KPAD + half * 16;
    int4 pre0 = ((const int4*)wsrc)[0];
    int4 pre1 = ((const int4*)wsrc)[1];

    const int mw = wave * 16 + l16;      // this lane's output row (w coordinate)

    for (int it = 0; it < NITER; ++it) {
        unsigned short* bsw = Bs + (it & 1) * BS_SZ;
        // write prefetched B tile (loads issued last iter; vmcnt waits here)
        {
            int4* d4 = (int4*)(bsw + bn * BS_STRIDE + half * 16);
            d4[0] = pre0;
            d4[1] = pre1;
        }
        __syncthreads();

        // issue next iter's B loads (in flight across the whole compute phase)
        if (it + 1 < NITER) {
            const int4* s4 = (const int4*)(wsrc + (it + 1) * 32);
            pre0 = s4[0];
            pre1 = s4[1];
        }

        // ---- features -> A fragment (1 scalar per lane) ----
        const int i  = it * 4 + quad;        // patch element for this quad
        const int c  = i / 9;
        const int s9 = i - c * 9;
        const int kh = s9 / 3;
        const int kw = s9 - kh * 3;

        float p = bf2f(Xs[(kh * XS_W + (mw + kw)) * XS_C + c]);

        float e   = __expf(-p);
        float sig = __builtin_amdgcn_rcpf(1.f + e);
        float f0  = p * sig;

        float u  = p * 1.5f + 4.5f;          // (p+3)*1.5
        float fj = floorf(u);
        int   j0 = (int)fj;
        float t  = u - fj;
        bool  inr = (u >= 0.f) & (u < 9.f);
        float t2 = t * t, t3 = t2 * t;
        const float c16 = 1.f / 6.f;
        float r0 = t3 * c16;
        float r1 = (-3.f * t3 + 3.f * t2 + 3.f * t + 1.f) * c16;
        float r2 = (3.f * t3 - 6.f * t2 + 4.f) * c16;
        float s1 = 1.f - t;
        float r3 = s1 * s1 * s1 * c16;

        unsigned short uf[8];
        uf[0] = f2bf(f0);
#pragma unroll
        for (int g = 0; g < 6; ++g) {
            int r = j0 - g;
            float v = (r == 0) ? r0 : ((r == 1) ? r1 : ((r == 2) ? r2 : ((r == 3) ? r3 : 0.f)));
            v = inr ? v : 0.f;
            uf[1 + g] = f2bf(v);
        }
        uf[7] = 0;
        short8 afrag;
#pragma unroll
        for (int e2 = 0; e2 < 8; ++e2) afrag[e2] = (short)uf[e2];

        // ---- MFMA over 8 n-subtiles ----
#pragma unroll
        for (int ns = 0; ns < 8; ++ns) {
            short8 bfrag = *(const short8*)(bsw + (ns * 16 + l16) * BS_STRIDE + quad * 8);
            acc[ns] = __builtin_amdgcn_mfma_f32_16x16x32_bf16(afrag, bfrag, acc[ns], 0, 0, 0);
        }
        // no second barrier: reads of this buffer finish before bar(it+1),
        // writes to it resume only after bar(it+1) (double buffer)
    }

    // ---- epilogue: C/D layout col=lane&15, row=quad*4+reg ----
    const size_t rowbase = (size_t)blk * 64 + wave * 16;
#pragma unroll
    for (int r = 0; r < 4; ++r) {
        size_t row = rowbase + quad * 4 + r;
        float* po = out + row * 128 + l16;
#pragma unroll
        for (int ns = 0; ns < 8; ++ns)
            po[ns * 16] = acc[ns][r] + bias_v[ns];
    }
}

extern "C" void kernel_launch(void* const* d_in, const int* in_sizes, int n_in,
                              void* d_out, int out_size, void* d_ws, size_t ws_size,
                              hipStream_t stream) {
    (void)in_sizes; (void)n_in; (void)out_size; (void)ws_size;
    const float* x        = (const float*)d_in[0];
    const float* base_w   = (const float*)d_in[1];
    const float* spline_w = (const float*)d_in[2];
    const float* bias     = (const float*)d_in[3];
    float* out = (float*)d_out;
    unsigned short* wbt = (unsigned short*)d_ws;   // 128*4608*2 = 1.13 MB

    hipLaunchKernelGGL(prep_w_kernel, dim3((OUT_CH * PATCH + 255) / 256), dim3(256), 0, stream,
                       base_w, spline_w, wbt);

    const int shmem = (3 * XS_W * XS_C + 2 * BS_SZ) * 2;   // 26928 + 20480 = 47408 B
    (void)hipFuncSetAttribute((const void*)convkan_main,
                              hipFuncAttributeMaxDynamicSharedMemorySize, shmem);
    hipLaunchKernelGGL(convkan_main, dim3(512), dim3(256), shmem, stream,
                       x, bias, wbt, out);
}

// Round 4
// 167.979 us; speedup vs baseline: 2.3305x; 1.5234x over previous
//
#include <hip/hip_runtime.h>

typedef __attribute__((ext_vector_type(8))) short short8;
typedef __attribute__((ext_vector_type(16))) float f32x16;

#define NITER 144
#define FT_SHORTS (64u*8u*64u*64u*8u)   // Ft[c][b][y][x][8] bf16 = 16,777,216 shorts (33.55 MB)
// ws layout: [Ft 33.55MB][wbt_tiled 144*128*32*2B = 1.18MB][8KB over-read slack]

typedef __attribute__((address_space(3))) unsigned int lds_u32_t;
typedef __attribute__((address_space(1))) const unsigned int g_u32_t;

__device__ __forceinline__ unsigned short f2bf(float x) {
    union { float f; unsigned u; } v; v.f = x;
    unsigned r = v.u + 0x7FFFu + ((v.u >> 16) & 1u);   // RNE bf16
    return (unsigned short)(r >> 16);
}

// 7 features of p: silu, 6 cubic B-spline bases (uniform knots -3 + j*2/3), +1 zero pad
__device__ __forceinline__ void feat8(float p, unsigned short* uf) {
    float e   = __expf(-p);
    float sig = 1.f / (1.f + e);
    uf[0] = f2bf(p * sig);
    float u  = p * 1.5f + 4.5f;          // (p+3)*1.5
    float fj = floorf(u);
    int   j0 = (int)fj;
    float t  = u - fj;
    bool  inr = (u >= 0.f) && (u < 9.f);
    float t2 = t * t, t3 = t2 * t;
    const float c16 = 1.f / 6.f;
    float r0 = t3 * c16;
    float r1 = (-3.f * t3 + 3.f * t2 + 3.f * t + 1.f) * c16;
    float r2 = (3.f * t3 - 6.f * t2 + 4.f) * c16;
    float s1 = 1.f - t;
    float r3 = s1 * s1 * s1 * c16;
#pragma unroll
    for (int g = 0; g < 6; ++g) {
        int r = j0 - g;
        float v = (r == 0) ? r0 : ((r == 1) ? r1 : ((r == 2) ? r2 : ((r == 3) ? r3 : 0.f)));
        uf[1 + g] = f2bf(inr ? v : 0.f);
    }
    uf[7] = 0;
}

// ---- Build tiled+swizzled B: wt[it][n][ch*8+f], ch = (i&3) ^ ((n>>1)&3), it = i>>2 ----
__global__ void prep_w(const float* __restrict__ bw, const float* __restrict__ sw,
                       unsigned short* __restrict__ wt) {
    int idx = blockIdx.x * 256 + threadIdx.x;
    if (idx >= 128 * 576) return;
    int o = idx / 576;
    int i = idx - o * 576;
    int it = i >> 2, k8 = i & 3;
    int ch = k8 ^ ((o >> 1) & 3);
    union { unsigned short u[8]; uint4 v; } pk;
    pk.u[0] = f2bf(bw[o * 576 + i]);
    const float* s = sw + (size_t)(o * 576 + i) * 6;
#pragma unroll
    for (int f = 0; f < 6; ++f) pk.u[1 + f] = f2bf(s[f]);
    pk.u[7] = 0;
    *(uint4*)(wt + ((size_t)(it * 128 + o) * 32 + ch * 8)) = pk.v;
}

// ---- Features once per x element: Ft[c][b][y][x][8] ----
__global__ __launch_bounds__(256)
void feat_k(const float* __restrict__ x, unsigned short* __restrict__ ft) {
    __shared__ float Xl[64 * 65];        // [w][c] padded +1 -> conflict-free
    const int line = blockIdx.x;         // b*64 + y
    const int b = line >> 6, y = line & 63;
    const float* xl = x + (size_t)line * 4096;
    const int tid = threadIdx.x;
    for (int f4 = tid; f4 < 1024; f4 += 256) {
        float4 v = ((const float4*)xl)[f4];
        int xx = f4 >> 4, c4 = (f4 & 15) << 2;
        float* d = &Xl[xx * 65 + c4];
        d[0] = v.x; d[1] = v.y; d[2] = v.z; d[3] = v.w;
    }
    __syncthreads();
    const int xx = tid & 63;
    const int cw = tid >> 6;
#pragma unroll 4
    for (int p = 0; p < 16; ++p) {
        int c = cw + (p << 2);
        float pv = Xl[xx * 65 + c];
        union { unsigned short u[8]; uint4 v; } pk;
        feat8(pv, pk.u);
        size_t o16 = ((size_t)(c * 8 + b) << 12) + (y << 6) + xx;
        *(uint4*)(ft + (o16 << 3)) = pk.v;
    }
}

// A-fragment: lane reads 16B = 8 features of patch-elem i for its output pixel.
// Out-of-range taps (SAME zero-padding): features of p=0, NOT zero!
// feat8(0): silu=0; u=4.5,t=0.5 -> bases = [0, 1/48, 23/48, 23/48, 1/48, 0]
// bf16(1/48)=0x3CAB, bf16(23/48)=0x3EF5 (RNE)
__device__ __forceinline__ short8 load_a(const unsigned short* __restrict__ ft,
                                         int i, int ybase, int xbase, int base16) {
    int c  = (i * 7282) >> 16;           // i/9 exact for i<5000
    int i9 = i - c * 9;
    int kh = (i9 * 11) >> 5;             // i9/3 exact for i9<9
    int kw = i9 - kh * 3;
    short8 v = { 0, 0, (short)0x3CAB, (short)0x3EF5,
                 (short)0x3EF5, (short)0x3CAB, 0, 0 };   // feat8(0) pad fragment
    if (((unsigned)(ybase + kh) < 64u) && ((unsigned)(xbase + kw) < 64u)) {
        int a16 = (c << 15) + (kh << 6) + kw + base16;
        v = *(const short8*)(ft + ((size_t)a16 << 3));
    }
    return v;
}

// ---- Main GEMM: grid 256, block 512 (8 waves as 4m x 2n), tile 128m x 128n ----
// wave = 32m x 64n via mfma_f32_32x32x16_bf16 (2 n-subtiles, acc 32 VGPR)
__global__ __launch_bounds__(512, 2)
void convkan_gemm(const unsigned short* __restrict__ ft,
                  const unsigned short* __restrict__ wt,
                  const float* __restrict__ bias,
                  float* __restrict__ out) {
    __shared__ unsigned short Bs[2 * 128 * 32];   // double-buffered B slab, 16 KB

    const int tid  = threadIdx.x;
    const int blk  = blockIdx.x;
    const int lane = tid & 63;
    const int wave = tid >> 6;       // 0..7
    const int mi   = wave >> 1;      // 0..3 (m-group of 32 rows)
    const int ni   = wave & 1;       // 0..1 (n-group of 64 cols)
    const int l32  = lane & 31;
    const int h    = lane >> 5;      // k-half within frag

    const int b  = blk >> 5;
    const int h0 = (blk & 31) << 1;  // block covers image lines h0, h0+1
    const int ybase  = h0 + (mi >> 1) - 1;
    const int xbase  = ((mi & 1) << 5) + l32 - 1;
    const int base16 = (b << 12) + (ybase << 6) + xbase;

    // B staging: wave w stages rows 16w..16w+15 (1 KB) via global_load_lds
    const unsigned short* gB0 = wt + wave * 512 + lane * 8;
    unsigned short* ldsB = Bs + wave * 512;                 // buf0; buf1 = +4096 shorts

    // Loop-invariant B-frag LDS byte offsets (swizzled, bank-balanced)
    const int sw_   = (l32 >> 1) & 3;
    const int rowoff = (ni << 12) + (l32 << 6);             // ni*4096 + l32*64 bytes
    const int offk0 = rowoff + (((0 + h) ^ sw_) << 4);      // patch elems 0,1 of slab
    const int offk1 = rowoff + (((2 + h) ^ sw_) << 4);      // patch elems 2,3 of slab

    f32x16 acc0, acc1;
#pragma unroll
    for (int e = 0; e < 16; ++e) { acc0[e] = 0.f; acc1[e] = 0.f; }

    // prologue: slab 0 -> buf0, A-frags for it=0
    __builtin_amdgcn_global_load_lds((g_u32_t*)gB0, (lds_u32_t*)ldsB, 16, 0, 0);
    const unsigned short* gB = gB0 + 4096;
    short8 a0 = load_a(ft, 0 + h, ybase, xbase, base16);
    short8 a1 = load_a(ft, 2 + h, ybase, xbase, base16);

    for (int it = 0; it < NITER; ++it) {
        __syncthreads();   // slab(it) resident; buf((it+1)&1) free
        // prefetch it+1 (last iter over-reads into ws slack; results unused)
        {
            unsigned short* l = ldsB + (((it + 1) & 1) << 12);
            __builtin_amdgcn_global_load_lds((g_u32_t*)gB, (lds_u32_t*)l, 16, 0, 0);
            gB += 4096;
        }
        const int i1 = (it + 1) << 2;
        short8 an0 = load_a(ft, i1 + h,     ybase, xbase, base16);
        short8 an1 = load_a(ft, i1 + 2 + h, ybase, xbase, base16);

        const char* bb = (const char*)Bs + ((it & 1) << 13);
        short8 bf00 = *(const short8*)(bb + offk0);
        short8 bf10 = *(const short8*)(bb + 2048 + offk0);
        short8 bf01 = *(const short8*)(bb + offk1);
        short8 bf11 = *(const short8*)(bb + 2048 + offk1);
        acc0 = __builtin_amdgcn_mfma_f32_32x32x16_bf16(a0, bf00, acc0, 0, 0, 0);
        acc1 = __builtin_amdgcn_mfma_f32_32x32x16_bf16(a0, bf10, acc1, 0, 0, 0);
        acc0 = __builtin_amdgcn_mfma_f32_32x32x16_bf16(a1, bf01, acc0, 0, 0, 0);
        acc1 = __builtin_amdgcn_mfma_f32_32x32x16_bf16(a1, bf11, acc1, 0, 0, 0);
        a0 = an0; a1 = an1;
    }

    // epilogue: C/D layout col=lane&31, row=(reg&3)+8*(reg>>2)+4*(lane>>5)
    const float b0v = bias[ni * 64 + l32];
    const float b1v = bias[ni * 64 + 32 + l32];
    const int mbase = blk * 128 + mi * 32 + h * 4;
    float* op = out + (size_t)mbase * 128 + ni * 64 + l32;
#pragma unroll
    for (int r = 0; r < 16; ++r) {
        int row = (r & 3) + ((r >> 2) << 3);
        op[(size_t)row * 128]      = acc0[r] + b0v;
        op[(size_t)row * 128 + 32] = acc1[r] + b1v;
    }
}

extern "C" void kernel_launch(void* const* d_in, const int* in_sizes, int n_in,
                              void* d_out, int out_size, void* d_ws, size_t ws_size,
                              hipStream_t stream) {
    (void)in_sizes; (void)n_in; (void)out_size; (void)ws_size;
    const float* x        = (const float*)d_in[0];
    const float* base_w   = (const float*)d_in[1];
    const float* spline_w = (const float*)d_in[2];
    const float* bias     = (const float*)d_in[3];
    float* out = (float*)d_out;

    unsigned short* ft = (unsigned short*)d_ws;            // 33.55 MB
    unsigned short* wt = ft + FT_SHORTS;                   // 1.18 MB (+8 KB slack used)

    hipLaunchKernelGGL(prep_w, dim3((128 * 576 + 255) / 256), dim3(256), 0, stream,
                       base_w, spline_w, wt);
    hipLaunchKernelGGL(feat_k, dim3(512), dim3(256), 0, stream, x, ft);
    hipLaunchKernelGGL(convkan_gemm, dim3(256), dim3(512), 0, stream,
                       ft, wt, bias, out);
}

// Round 6
// 159.552 us; speedup vs baseline: 2.4536x; 1.0528x over previous
//
#include <hip/hip_runtime.h>

typedef __attribute__((ext_vector_type(8))) short short8;
typedef __attribute__((ext_vector_type(16))) float f32x16;

// ws layout:
//   Ft2  [z=512][yy=66][xx=66][8] bf16 halo-padded features, z = c*8 + b   (35.68 MB)
//   wt2  [slab=72][n=128][64] bf16 swizzled B slabs (LDS image)            (1.18 MB)
#define FT2_SHORTS (512u * 4356u * 8u)     // 17,842,176
#define PLANE16    4356                     // 66*66 (16B units per z-plane)

typedef __attribute__((address_space(3))) unsigned int lds_u32_t;
typedef __attribute__((address_space(1))) const unsigned int g_u32_t;

__device__ __forceinline__ unsigned short f2bf(float x) {
    union { float f; unsigned u; } v; v.f = x;
    unsigned r = v.u + 0x7FFFu + ((v.u >> 16) & 1u);   // RNE bf16
    return (unsigned short)(r >> 16);
}

// 7 features of p: silu, 6 cubic B-spline bases (uniform knots -3 + j*2/3), + zero pad
__device__ __forceinline__ void feat8(float p, unsigned short* uf) {
    float e   = __expf(-p);
    float sig = 1.f / (1.f + e);
    uf[0] = f2bf(p * sig);
    float u  = p * 1.5f + 4.5f;
    float fj = floorf(u);
    int   j0 = (int)fj;
    float t  = u - fj;
    bool  inr = (u >= 0.f) && (u < 9.f);
    float t2 = t * t, t3 = t2 * t;
    const float c16 = 1.f / 6.f;
    float r0 = t3 * c16;
    float r1 = (-3.f * t3 + 3.f * t2 + 3.f * t + 1.f) * c16;
    float r2 = (3.f * t3 - 6.f * t2 + 4.f) * c16;
    float s1 = 1.f - t;
    float r3 = s1 * s1 * s1 * c16;
#pragma unroll
    for (int g = 0; g < 6; ++g) {
        int r = j0 - g;
        float v = (r == 0) ? r0 : ((r == 1) ? r1 : ((r == 2) ? r2 : ((r == 3) ? r3 : 0.f)));
        uf[1 + g] = f2bf(inr ? v : 0.f);
    }
    uf[7] = 0;
}

// ---- B prep: wt2[slab][n][chunk_phys*8+f], slab=i>>3, chunk_phys=(i&7)^(n&7) ----
__global__ void prep_w(const float* __restrict__ bw, const float* __restrict__ sw,
                       unsigned short* __restrict__ wt) {
    int idx = blockIdx.x * 256 + threadIdx.x;
    if (idx >= 128 * 576) return;
    int o = idx / 576;
    int i = idx - o * 576;
    int slab = i >> 3, e = i & 7;
    int ch = e ^ (o & 7);
    union { unsigned short u[8]; uint4 v; } pk;
    pk.u[0] = f2bf(bw[o * 576 + i]);
    const float* s = sw + (size_t)(o * 576 + i) * 6;
#pragma unroll
    for (int f = 0; f < 6; ++f) pk.u[1 + f] = f2bf(s[f]);
    pk.u[7] = 0;
    *(uint4*)(wt + ((size_t)slab * 8192 + o * 64 + ch * 8)) = pk.v;
}

// ---- Halo fill: feat8(0) = {0,0,1/48,23/48,23/48,1/48,0,0} into the 260 border cells ----
// ROUND-6 FIX: 260 cells > 256 threads -> grid-stride loop (cells 256..259 were
// left poisoned before = missing pad-spline terms on bottom-right edge, absmax 1.18)
__global__ void halo_k(unsigned short* __restrict__ ft) {
    int z = blockIdx.x;          // 512 planes
    for (int t = threadIdx.x; t < 260; t += 256) {
        int yy, xx;
        if (t < 66)       { yy = 0;       xx = t; }
        else if (t < 132) { yy = 65;      xx = t - 66; }
        else if (t < 196) { yy = t - 131; xx = 0; }    // 1..64
        else              { yy = t - 195; xx = 65; }   // 1..64
        short8 pad = { 0, 0, (short)0x3CAB, (short)0x3EF5,
                       (short)0x3EF5, (short)0x3CAB, 0, 0 };
        ((short8*)ft)[z * PLANE16 + yy * 66 + xx] = pad;
    }
}

// ---- Features once per x element into halo layout ----
__global__ __launch_bounds__(256)
void feat_k(const float* __restrict__ x, unsigned short* __restrict__ ft) {
    __shared__ float Xl[64 * 65];        // [w][c] padded -> conflict-free
    const int line = blockIdx.x;         // b*64 + y
    const int b = line >> 6, y = line & 63;
    const float* xl = x + (size_t)line * 4096;
    const int tid = threadIdx.x;
    for (int f4 = tid; f4 < 1024; f4 += 256) {
        float4 v = ((const float4*)xl)[f4];
        int xx = f4 >> 4, c4 = (f4 & 15) << 2;
        float* d = &Xl[xx * 65 + c4];
        d[0] = v.x; d[1] = v.y; d[2] = v.z; d[3] = v.w;
    }
    __syncthreads();
    const int xx = tid & 63;
    const int cw = tid >> 6;
#pragma unroll 4
    for (int p = 0; p < 16; ++p) {
        int c = cw + (p << 2);
        float pv = Xl[xx * 65 + c];
        union { unsigned short u[8]; uint4 v; } pk;
        feat8(pv, pk.u);
        size_t o16 = (size_t)(c * 8 + b) * PLANE16 + (y + 1) * 66 + (xx + 1);
        *(uint4*)(ft + (o16 << 3)) = pk.v;
    }
}

// ---- Main GEMM: grid 256, block 256 (4 waves as 2m x 2n), tile 128m x 128n ----
// wave = 64m x 64n: per k-step 2 A-frags (global, halo-padded) + 2 B-frags (LDS) + 4 MFMA
#define STAGE(itn)                                                               \
    {                                                                            \
        const unsigned short* ssrc = wt + (size_t)(itn) * 8192 + stoff;          \
        unsigned short* sdst = &Bs[((itn) & 1) ? 8192 : 0] + stoff;              \
        _Pragma("unroll")                                                        \
        for (int j = 0; j < 4; ++j)                                              \
            __builtin_amdgcn_global_load_lds((g_u32_t*)(ssrc + j * 2048),        \
                                             (lds_u32_t*)(sdst + j * 2048), 16, 0, 0); \
    }

#define ALOAD(itn, ADST)                                                         \
    _Pragma("unroll")                                                            \
    for (int s_ = 0; s_ < 4; ++s_) {                                             \
        int i_  = (itn) * 8 + s_ * 2 + h;                                        \
        int c_  = (i_ * 7282) >> 16;                                             \
        int i9_ = i_ - c_ * 9;                                                   \
        int kh_ = (i9_ * 11) >> 5;                                               \
        int kw_ = i9_ - kh_ * 3;                                                 \
        int t16 = c_ * (8 * PLANE16) + kh_ * 66 + kw_ + abase;                   \
        ADST[2 * s_]     = fptr[t16];                                            \
        ADST[2 * s_ + 1] = fptr[t16 + 32];                                       \
    }

#define KSTEP(s_, ACUR)                                                          \
    {                                                                            \
        short8 bf0 = *(const short8*)(bsrd + roff0 + ((((s_) * 2 + h) ^ swb) << 4)); \
        short8 bf1 = *(const short8*)(bsrd + roff1 + ((((s_) * 2 + h) ^ swb) << 4)); \
        acc00 = __builtin_amdgcn_mfma_f32_32x32x16_bf16(ACUR[2*(s_)],   bf0, acc00, 0, 0, 0); \
        acc01 = __builtin_amdgcn_mfma_f32_32x32x16_bf16(ACUR[2*(s_)],   bf1, acc01, 0, 0, 0); \
        acc10 = __builtin_amdgcn_mfma_f32_32x32x16_bf16(ACUR[2*(s_)+1], bf0, acc10, 0, 0, 0); \
        acc11 = __builtin_amdgcn_mfma_f32_32x32x16_bf16(ACUR[2*(s_)+1], bf1, acc11, 0, 0, 0); \
    }

__global__ __launch_bounds__(256, 1)
void convkan_gemm(const unsigned short* __restrict__ ft,
                  const unsigned short* __restrict__ wt,
                  const float* __restrict__ bias,
                  float* __restrict__ out) {
    __shared__ unsigned short Bs[2 * 8192];     // 2 x 16 KB B slabs (K=64 each)

    const int tid  = threadIdx.x;
    const int blk  = blockIdx.x;                 // 256 blocks
    const int lane = tid & 63;
    const int wave = tid >> 6;                   // 0..3
    const int g    = wave >> 1;                  // m-group: image line h0+g
    const int ni   = wave & 1;                   // n-group of 64
    const int l32  = lane & 31;
    const int h    = lane >> 5;                  // k-half

    const int b  = blk >> 5;
    const int h0 = (blk & 31) << 1;
    // lane A base (16B units): halo folds the -1 offset:
    // addr16 = c*8*PLANE16 + b*PLANE16 + (h0+g+kh)*66 + (ms*32 + l32 + kw)
    const int abase = b * PLANE16 + (h0 + g) * 66 + l32;
    const short8* fptr = (const short8*)ft;

    const int stoff = wave * 512 + lane * 8;     // staging offset (shorts)

    // B-frag LDS offsets (bytes): row n = ni*64 + ns*32 + l32, 128 B/row
    const int roff0 = (ni * 64 + l32) * 128;
    const int roff1 = roff0 + 32 * 128;
    const int swb   = l32 & 7;

    f32x16 acc00, acc01, acc10, acc11;
#pragma unroll
    for (int e = 0; e < 16; ++e) { acc00[e] = 0.f; acc01[e] = 0.f; acc10[e] = 0.f; acc11[e] = 0.f; }

    short8 aA[8], aB[8];
    STAGE(0);
    ALOAD(0, aA);

    for (int it = 0; it < 72; it += 2) {
        __syncthreads();                          // slab(it) resident in buf0
        STAGE(it + 1);                            // it+1 <= 71 always
        ALOAD(it + 1, aB);
        {
            const char* bsrd = (const char*)Bs;   // buf0
            KSTEP(0, aA) KSTEP(1, aA) KSTEP(2, aA) KSTEP(3, aA)
        }
        __syncthreads();                          // slab(it+1) resident in buf1
        if (it + 2 < 72) {
            STAGE(it + 2);
            ALOAD(it + 2, aA);
        }
        {
            const char* bsrd = (const char*)Bs + 16384;   // buf1
            KSTEP(0, aB) KSTEP(1, aB) KSTEP(2, aB) KSTEP(3, aB)
        }
    }

    // epilogue: C/D row = (r&3) + 8*(r>>2) + 4*h (+ ms*32), col = l32 (+ ns*32)
    const float bv0 = bias[ni * 64 + l32];
    const float bv1 = bias[ni * 64 + 32 + l32];
    const int mrow0 = blk * 128 + g * 64 + h * 4;
    float* o0 = out + (size_t)mrow0 * 128 + ni * 64 + l32;
#pragma unroll
    for (int r = 0; r < 16; ++r) {
        int row = (r & 3) + ((r >> 2) << 3);
        o0[(size_t)row * 128]             = acc00[r] + bv0;
        o0[(size_t)row * 128 + 32]        = acc01[r] + bv1;
        o0[(size_t)(row + 32) * 128]      = acc10[r] + bv0;
        o0[(size_t)(row + 32) * 128 + 32] = acc11[r] + bv1;
    }
}

extern "C" void kernel_launch(void* const* d_in, const int* in_sizes, int n_in,
                              void* d_out, int out_size, void* d_ws, size_t ws_size,
                              hipStream_t stream) {
    (void)in_sizes; (void)n_in; (void)out_size; (void)ws_size;
    const float* x        = (const float*)d_in[0];
    const float* base_w   = (const float*)d_in[1];
    const float* spline_w = (const float*)d_in[2];
    const float* bias     = (const float*)d_in[3];
    float* out = (float*)d_out;

    unsigned short* ft = (unsigned short*)d_ws;      // 35.68 MB halo features
    unsigned short* wt = ft + FT2_SHORTS;            // 1.18 MB tiled B

    hipLaunchKernelGGL(prep_w, dim3((128 * 576 + 255) / 256), dim3(256), 0, stream,
                       base_w, spline_w, wt);
    hipLaunchKernelGGL(halo_k, dim3(512), dim3(256), 0, stream, ft);
    hipLaunchKernelGGL(feat_k, dim3(512), dim3(256), 0, stream, x, ft);
    hipLaunchKernelGGL(convkan_gemm, dim3(256), dim3(256), 0, stream,
                       ft, wt, bias, out);
}